// Round 1
// baseline (267.558 us; speedup 1.0000x reference)
//
#include <hip/hip_runtime.h>
#include <math.h>

#define B 256
#define V 128000
#define VVEC (V / 4)          // 32000 float4 per row
#define NOISE_MIN 1e-10f
#define BLOCK 1024            // 16 waves

__device__ __forceinline__ void upd(float v, int i, float& bv, int& bi) {
    // first-occurrence argmax semantics: strictly greater wins; equal -> smaller index
    if (v > bv || (v == bv && i < bi)) { bv = v; bi = i; }
}

__global__ __launch_bounds__(BLOCK) void sampler_kernel(
    const float* __restrict__ logits,
    const float* __restrict__ temps,
    const float* __restrict__ noise,
    int* __restrict__ out)
{
    const int row = blockIdx.x;
    const float t = temps[row];
    const bool greedy = (t <= 0.0f);          // block-uniform branch
    const float invT = greedy ? 1.0f : (1.0f / t);

    const size_t base = (size_t)row * V;
    const float4* __restrict__ lg = reinterpret_cast<const float4*>(logits + base);
    const float4* __restrict__ nz = reinterpret_cast<const float4*>(noise + base);

    float bestVal = -INFINITY;
    int   bestIdx = 0x7FFFFFFF;

    if (greedy) {
        // greedy rows: pure argmax of logits, skip noise traffic entirely
        for (int v = threadIdx.x; v < VVEC; v += BLOCK) {
            float4 l = lg[v];
            int i0 = v << 2;
            upd(l.x, i0 + 0, bestVal, bestIdx);
            upd(l.y, i0 + 1, bestVal, bestIdx);
            upd(l.z, i0 + 2, bestVal, bestIdx);
            upd(l.w, i0 + 3, bestVal, bestIdx);
        }
    } else {
        // sampled rows: argmax( l/t - log(max(noise, 1e-10)) )
        for (int v = threadIdx.x; v < VVEC; v += BLOCK) {
            float4 l = lg[v];
            float4 n = nz[v];
            int i0 = v << 2;
            float kx = l.x * invT - __logf(fmaxf(n.x, NOISE_MIN));
            float ky = l.y * invT - __logf(fmaxf(n.y, NOISE_MIN));
            float kz = l.z * invT - __logf(fmaxf(n.z, NOISE_MIN));
            float kw = l.w * invT - __logf(fmaxf(n.w, NOISE_MIN));
            upd(kx, i0 + 0, bestVal, bestIdx);
            upd(ky, i0 + 1, bestVal, bestIdx);
            upd(kz, i0 + 2, bestVal, bestIdx);
            upd(kw, i0 + 3, bestVal, bestIdx);
        }
    }

    // wave (64-lane) reduction
    #pragma unroll
    for (int off = 32; off > 0; off >>= 1) {
        float ov = __shfl_down(bestVal, off, 64);
        int   oi = __shfl_down(bestIdx, off, 64);
        if (ov > bestVal || (ov == bestVal && oi < bestIdx)) { bestVal = ov; bestIdx = oi; }
    }

    // cross-wave reduction (16 waves)
    __shared__ float sVal[BLOCK / 64];
    __shared__ int   sIdx[BLOCK / 64];
    const int wave = threadIdx.x >> 6;
    const int lane = threadIdx.x & 63;
    if (lane == 0) { sVal[wave] = bestVal; sIdx[wave] = bestIdx; }
    __syncthreads();

    if (wave == 0) {
        const int nw = BLOCK / 64;   // 16
        bestVal = (lane < nw) ? sVal[lane] : -INFINITY;
        bestIdx = (lane < nw) ? sIdx[lane] : 0x7FFFFFFF;
        #pragma unroll
        for (int off = 8; off > 0; off >>= 1) {
            float ov = __shfl_down(bestVal, off, 64);
            int   oi = __shfl_down(bestIdx, off, 64);
            if (ov > bestVal || (ov == bestVal && oi < bestIdx)) { bestVal = ov; bestIdx = oi; }
        }
        if (lane == 0) out[row] = bestIdx;
    }
}

extern "C" void kernel_launch(void* const* d_in, const int* in_sizes, int n_in,
                              void* d_out, int out_size, void* d_ws, size_t ws_size,
                              hipStream_t stream) {
    const float* logits = (const float*)d_in[0];   // [B, V] f32
    const float* temps  = (const float*)d_in[1];   // [B]    f32
    const float* noise  = (const float*)d_in[2];   // [B, V] f32
    int* out = (int*)d_out;                        // [B] int32 (jax int64 -> int32, x64 off)

    sampler_kernel<<<B, BLOCK, 0, stream>>>(logits, temps, noise, out);
}